// Round 1
// baseline (4162.994 us; speedup 1.0000x reference)
//
#include <hip/hip_runtime.h>
#include <math.h>

#define DD 128   // node / hidden dim
#define FF 64    // edge feature dim

__device__ __forceinline__ float ssp_f(float x) {
    // softplus(x) - ln(2), numerically stable
    float ax = fabsf(x);
    float e  = __expf(-ax);
    return fmaxf(x, 0.0f) + __logf(1.0f + e) - 0.6931471805599453f;
}

__global__ void copy_nodes_kernel(const float4* __restrict__ src,
                                  float4* __restrict__ dst, int n4) {
    int i = blockIdx.x * blockDim.x + threadIdx.x;
    int stride = gridDim.x * blockDim.x;
    for (; i < n4; i += stride) dst[i] = src[i];
}

__launch_bounds__(256, 2)
__global__ void edge_fused_kernel(const float* __restrict__ nodes,
                                  const float* __restrict__ edges,
                                  const int*   __restrict__ eidx,
                                  const float* __restrict__ W1,
                                  const float* __restrict__ b1,
                                  const float* __restrict__ W2,
                                  const float* __restrict__ b2,
                                  float* __restrict__ out,
                                  int E) {
    int e = blockIdx.x * 256 + threadIdx.x;
    if (e >= E) return;

    int ns = eidx[2 * e + 0];   // scatter target (starts)
    int nt = eidx[2 * e + 1];   // gather source (ends)

    // ---- GEMM1: h1 = ssp(edges[e] @ W1 + b1), h1 in 128 VGPRs ----
    float h1[DD];
    #pragma unroll
    for (int d = 0; d < DD; ++d) h1[d] = b1[d];

    const float4* ev4 = reinterpret_cast<const float4*>(edges) + (size_t)e * (FF / 4);
    #pragma unroll 1
    for (int f4 = 0; f4 < FF / 4; ++f4) {
        float4 ev = ev4[f4];
        const float* w0 = W1 + (size_t)(f4 * 4) * DD;
        #pragma unroll
        for (int d = 0; d < DD; ++d) h1[d] = fmaf(ev.x, w0[d], h1[d]);
        #pragma unroll
        for (int d = 0; d < DD; ++d) h1[d] = fmaf(ev.y, w0[DD + d], h1[d]);
        #pragma unroll
        for (int d = 0; d < DD; ++d) h1[d] = fmaf(ev.z, w0[2 * DD + d], h1[d]);
        #pragma unroll
        for (int d = 0; d < DD; ++d) h1[d] = fmaf(ev.w, w0[3 * DD + d], h1[d]);
    }

    #pragma unroll
    for (int d = 0; d < DD; ++d) h1[d] = ssp_f(h1[d]);

    const float* nrow = nodes + (size_t)nt * DD;
    float*       orow = out   + (size_t)ns * DD;

    // ---- GEMM2 in two 64-wide output chunks to bound VGPR pressure ----
    #pragma unroll 1
    for (int c = 0; c < 2; ++c) {
        const int base = c * 64;
        float h2[64];
        #pragma unroll
        for (int j = 0; j < 64; ++j) h2[j] = b2[base + j];

        #pragma unroll
        for (int k = 0; k < DD; ++k) {           // fully unrolled: h1[k] stays in regs
            float hk = h1[k];
            const float* w = W2 + (size_t)k * DD + base;
            #pragma unroll
            for (int j = 0; j < 64; ++j) h2[j] = fmaf(hk, w[j], h2[j]);
        }

        #pragma unroll
        for (int j = 0; j < 64; ++j) {
            float m = ssp_f(h2[j]) * nrow[base + j];
            __hip_atomic_fetch_add(&orow[base + j], m,
                                   __ATOMIC_RELAXED, __HIP_MEMORY_SCOPE_AGENT);
        }
    }
}

extern "C" void kernel_launch(void* const* d_in, const int* in_sizes, int n_in,
                              void* d_out, int out_size, void* d_ws, size_t ws_size,
                              hipStream_t stream) {
    const float* nodes = (const float*)d_in[0];
    const float* edges = (const float*)d_in[1];
    const int*   eidx  = (const int*)  d_in[2];
    const float* W1    = (const float*)d_in[3];
    const float* b1    = (const float*)d_in[4];
    const float* W2    = (const float*)d_in[5];
    const float* b2    = (const float*)d_in[6];
    float* out = (float*)d_out;

    int ND = in_sizes[0];        // N*D
    int E  = in_sizes[1] / FF;   // 600000

    // out = nodes (copy), then scatter-add messages
    int n4 = ND / 4;
    copy_nodes_kernel<<<dim3(1024), dim3(256), 0, stream>>>(
        (const float4*)nodes, (float4*)out, n4);

    edge_fused_kernel<<<dim3((E + 255) / 256), dim3(256), 0, stream>>>(
        nodes, edges, eidx, W1, b1, W2, b2, out, E);
}